// Round 7
// baseline (262.236 us; speedup 1.0000x reference)
//
#include <hip/hip_runtime.h>
#include <math.h>

// Problem constants (fixed by setup_inputs)
#define BATCH   2
#define NS      8192
#define NT      2048
#define KNN     64
#define CH      64
#define SC      192           // NUM_SHELLS * CH
#define NPT     4096          // BATCH * NT
#define FST     72            // featsT row stride (bf16 elems)
#define KST     72            // kern row stride
#define NSLICE  8
#define CHUNKS  512           // 16384 points / 32 per chunk

typedef __attribute__((ext_vector_type(8))) short short8;
typedef __attribute__((ext_vector_type(4))) float f32x4;

// one-instruction packed f32->bf16 (RNE), lo -> bits[15:0], hi -> bits[31:16]
__device__ inline unsigned cvtpk(float lo, float hi) {
    unsigned r;
    asm("v_cvt_pk_bf16_f32 %0, %1, %2" : "=v"(r) : "v"(lo), "v"(hi));
    return r;
}
__device__ inline float blo(unsigned v) { return __uint_as_float(v << 16); }
__device__ inline float bhi(unsigned v) { return __uint_as_float(v & 0xffff0000u); }

// ---------------------------------------------------------------------------
// Kernel 1 (MFMA): UNCHANGED from round 5/6 (attribution control).
// y stored bf16, layout y[ys][pt][192]: each (ys,pt,s) 64-ch chunk = one
// 128 B cache line.
// ---------------------------------------------------------------------------
__global__ __launch_bounds__(256) void sh_conv_mfma(
    const float* __restrict__ src,      // (B,NS,CH)
    const float* __restrict__ patches,  // (B,NT,K,3)
    const float* __restrict__ pdist,    // (B,NT,K)
    const int*   __restrict__ pidx,     // (B,NT,K)
    unsigned short* __restrict__ y)     // (16, NPT, 192) bf16
{
    __shared__ unsigned short featsT[CH * FST];  // [c][k] 9216 B
    __shared__ unsigned short kern[48 * KST];    // [row48][k] 6912 B

    const int pt = blockIdx.x;           // b*NT + n
    const int b  = pt >> 11;             // NT = 2048
    const int t  = threadIdx.x;
    const int w  = t >> 6;               // wave 0..3
    const int l  = t & 63;               // lane

    // ---- Phase A1: gather + transpose into featsT[c=lane][k] ----
    {
        const int* idxp = pidx + pt * KNN;
        #pragma unroll
        for (int ko = 0; ko < 2; ++ko) {
            const int kbase = w * 16 + ko * 8;
            float v[8];
            #pragma unroll
            for (int j = 0; j < 8; ++j) {
                const int id = idxp[kbase + j];          // wave-uniform -> s_load
                v[j] = src[((size_t)(b * NS + id)) * CH + l];  // coalesced 256B row
            }
            uint4 pk;
            pk.x = cvtpk(v[0], v[1]);
            pk.y = cvtpk(v[2], v[3]);
            pk.z = cvtpk(v[4], v[5]);
            pk.w = cvtpk(v[6], v[7]);
            *(uint4*)&featsT[l * FST + kbase] = pk;      // ds_write_b128
        }
    }

    // ---- Phase A2: kern[row48 = ys*3+s][k] = bf16( sh[ys]*w[s]/64 ) ----
    {
        const int k  = l;
        const float* pv = patches + ((size_t)pt * KNN + k) * 3;
        const float px = pv[0], py = pv[1], pz = pv[2];
        const float d  = pdist[pt * KNN + k];
        const float inv = 1.0f / (d + 1e-8f);
        const float x = px * inv, yy = py * inv, z = pz * inv;
        const float x2 = x * x, y2 = yy * yy, z2 = z * z;

        float sh[16];
        sh[0]  = 0.28209479177387814f;
        sh[1]  = 0.4886025119029199f * yy;
        sh[2]  = 0.4886025119029199f * z;
        sh[3]  = 0.4886025119029199f * x;
        sh[4]  = 1.0925484305920792f * x * yy;
        sh[5]  = 1.0925484305920792f * yy * z;
        sh[6]  = 0.31539156525252005f * (3.0f * z2 - 1.0f);
        sh[7]  = 1.0925484305920792f * x * z;
        sh[8]  = 0.5462742152960396f * (x2 - y2);
        sh[9]  = 0.5900435899266435f * yy * (3.0f * x2 - y2);
        sh[10] = 2.890611442640554f  * x * yy * z;
        sh[11] = 0.4570457994644658f * yy * (5.0f * z2 - 1.0f);
        sh[12] = 0.3731763325901154f * z * (5.0f * z2 - 3.0f);
        sh[13] = 0.4570457994644658f * x * (5.0f * z2 - 1.0f);
        sh[14] = 1.445305721320277f  * z * (x2 - y2);
        sh[15] = 0.5900435899266435f * x * (x2 - 3.0f * y2);

        // exp(-ln2*9*t^2) == exp2(-9*t^2): one v_exp_f32 each
        float w0 = exp2f(-9.0f * d * d);
        const float dm1 = d - 0.5f;
        float w1 = exp2f(-9.0f * dm1 * dm1);
        const float dm2 = d - 1.0f;
        float w2 = exp2f(-9.0f * dm2 * dm2);
        const float wn = ((d <= 1.0f) ? 1.0f : 0.0f) * (1.0f / 64.0f)
                         / (w0 + w1 + w2 + 1e-8f);  // fold 1/K
        w0 *= wn; w1 *= wn; w2 *= wn;

        const int ys0 = w * 4;           // this wave's ys quarter
        #pragma unroll
        for (int i = 0; i < 4; ++i) {
            const float s = sh[ys0 + i];
            const int r0 = (ys0 + i) * 3;
            const float p0 = s * w0, p1 = s * w1, p2 = s * w2;
            kern[(r0 + 0) * KST + k] = (unsigned short)cvtpk(p0, p0);
            kern[(r0 + 1) * KST + k] = (unsigned short)cvtpk(p1, p1);
            kern[(r0 + 2) * KST + k] = (unsigned short)cvtpk(p2, p2);
        }
    }
    __syncthreads();

    // ---- Phase B: MFMA. lane: mhat = l&15, k-octet g = l>>4 ----
    const int mh = l & 15;
    const int g  = l >> 4;
    f32x4 acc0 = {0.f, 0.f, 0.f, 0.f};
    f32x4 acc1 = {0.f, 0.f, 0.f, 0.f};
    f32x4 acc2 = {0.f, 0.f, 0.f, 0.f};

    #pragma unroll
    for (int k0 = 0; k0 < 64; k0 += 32) {
        const int kofs = k0 + g * 8;
        const short8 af = *(const short8*)&featsT[(w * 16 + mh) * FST + kofs];
        const short8 b0 = *(const short8*)&kern[( 0 + mh) * KST + kofs];
        const short8 b1 = *(const short8*)&kern[(16 + mh) * KST + kofs];
        const short8 b2 = *(const short8*)&kern[(32 + mh) * KST + kofs];
        acc0 = __builtin_amdgcn_mfma_f32_16x16x32_bf16(af, b0, acc0, 0, 0, 0);
        acc1 = __builtin_amdgcn_mfma_f32_16x16x32_bf16(af, b1, acc1, 0, 0, 0);
        acc2 = __builtin_amdgcn_mfma_f32_16x16x32_bf16(af, b2, acc2, 0, 0, 0);
    }

    // ---- Store: lane reg r = Y^T[c = w*16+4g+r][row48 = tn*16+mh] ----
    {
        const int cbase = w * 16 + g * 4;
        #pragma unroll
        for (int tn = 0; tn < 3; ++tn) {
            const f32x4 a = (tn == 0) ? acc0 : (tn == 1) ? acc1 : acc2;
            const int row48 = tn * 16 + mh;
            const int ys = row48 / 3, s = row48 - ys * 3;
            uint2 o;
            o.x = cvtpk(a[0], a[1]);
            o.y = cvtpk(a[2], a[3]);
            *(uint2*)(y + ((size_t)ys * NPT + pt) * SC + s * CH + cbase) = o;
        }
    }
}

// ---------------------------------------------------------------------------
// Kernel 2 (XCC-queue): slices pinned to the PHYSICAL XCD via
// s_getreg(HW_REG_XCC_ID) + per-slice atomic work queues. Each block drains
// its own XCD's slice queue (perfect L2 locality by construction), then
// steals leftovers from other slices (correctness never depends on the
// dispatch pattern). Deterministic: each chunk computed identically once.
//   slice 0..2: (3,s)        slice 3..5: (2,s)+(0,s)
//   slice 6: (1,0)+(1,1)     slice 7: (1,2)
// Block: 256 thr = 32 points x 8 ch-groups (uint4 = 8 channels).
// ---------------------------------------------------------------------------
template<int L, int S>
__device__ inline void proc_group(const unsigned short* __restrict__ y,
                                  int t0, int t1, int t2,
                                  float w0, float w1, float w2,
                                  int cg, float* __restrict__ ob)
{
    float ns[8];
    #pragma unroll
    for (int j = 0; j < 8; ++j) ns[j] = 0.f;

    #pragma unroll
    for (int m = 0; m <= 2 * L; ++m) {
        const int ys = L * L + m;
        const size_t base = (size_t)ys * NPT * SC + S * CH + cg * 8;
        const uint4 A  = *(const uint4*)(y + base + (size_t)t0 * SC);
        const uint4 Bv = *(const uint4*)(y + base + (size_t)t1 * SC);
        const uint4 Cv = *(const uint4*)(y + base + (size_t)t2 * SC);
        const unsigned aw[4] = {A.x,  A.y,  A.z,  A.w};
        const unsigned bw[4] = {Bv.x, Bv.y, Bv.z, Bv.w};
        const unsigned cw[4] = {Cv.x, Cv.y, Cv.z, Cv.w};
        #pragma unroll
        for (int q = 0; q < 4; ++q) {
            const float vlo = w0 * blo(aw[q]) + w1 * blo(bw[q]) + w2 * blo(cw[q]);
            const float vhi = w0 * bhi(aw[q]) + w1 * bhi(bw[q]) + w2 * bhi(cw[q]);
            ns[2 * q]     += vlo * vlo;
            ns[2 * q + 1] += vhi * vhi;
        }
    }

    f32x4 o0, o1;
    o0[0] = sqrtf(fmaxf(ns[0], 1e-8f));
    o0[1] = sqrtf(fmaxf(ns[1], 1e-8f));
    o0[2] = sqrtf(fmaxf(ns[2], 1e-8f));
    o0[3] = sqrtf(fmaxf(ns[3], 1e-8f));
    o1[0] = sqrtf(fmaxf(ns[4], 1e-8f));
    o1[1] = sqrtf(fmaxf(ns[5], 1e-8f));
    o1[2] = sqrtf(fmaxf(ns[6], 1e-8f));
    o1[3] = sqrtf(fmaxf(ns[7], 1e-8f));
    float* p = ob + L * SC + S * CH + cg * 8;
    __builtin_nontemporal_store(o0, (f32x4*)p);
    __builtin_nontemporal_store(o1, (f32x4*)(p + 4));
}

__device__ inline void do_point(int slice, const unsigned short* __restrict__ y,
                                const int* __restrict__ prop_idx,
                                const float* __restrict__ prop_dist,
                                float* __restrict__ out, int pt, int cg)
{
    const int b = pt >> 13;               // NS = 8192
    const int   i0 = prop_idx[pt * 3 + 0];
    const int   i1 = prop_idx[pt * 3 + 1];
    const int   i2 = prop_idx[pt * 3 + 2];
    const float d0 = prop_dist[pt * 3 + 0];
    const float d1 = prop_dist[pt * 3 + 1];
    const float d2 = prop_dist[pt * 3 + 2];

    float w0 = 1.0f / (d0 * d0 + 1e-8f);
    float w1 = 1.0f / (d1 * d1 + 1e-8f);
    float w2 = 1.0f / (d2 * d2 + 1e-8f);
    const float wi = 1.0f / (w0 + w1 + w2);
    w0 *= wi; w1 *= wi; w2 *= wi;

    const int t0 = b * NT + i0;
    const int t1 = b * NT + i1;
    const int t2 = b * NT + i2;
    float* ob = out + (size_t)pt * (4 * SC);

    switch (slice) {
    case 0: proc_group<3, 0>(y, t0, t1, t2, w0, w1, w2, cg, ob); break;
    case 1: proc_group<3, 1>(y, t0, t1, t2, w0, w1, w2, cg, ob); break;
    case 2: proc_group<3, 2>(y, t0, t1, t2, w0, w1, w2, cg, ob); break;
    case 3: proc_group<2, 0>(y, t0, t1, t2, w0, w1, w2, cg, ob);
            proc_group<0, 0>(y, t0, t1, t2, w0, w1, w2, cg, ob); break;
    case 4: proc_group<2, 1>(y, t0, t1, t2, w0, w1, w2, cg, ob);
            proc_group<0, 1>(y, t0, t1, t2, w0, w1, w2, cg, ob); break;
    case 5: proc_group<2, 2>(y, t0, t1, t2, w0, w1, w2, cg, ob);
            proc_group<0, 2>(y, t0, t1, t2, w0, w1, w2, cg, ob); break;
    case 6: proc_group<1, 0>(y, t0, t1, t2, w0, w1, w2, cg, ob);
            proc_group<1, 1>(y, t0, t1, t2, w0, w1, w2, cg, ob); break;
    default:proc_group<1, 2>(y, t0, t1, t2, w0, w1, w2, cg, ob); break;
    }
}

__global__ __launch_bounds__(256) void prop_norm_xcc(
    const unsigned short* __restrict__ y, // (16, NPT, 192) bf16
    const int*   __restrict__ prop_idx,   // (B,NS,3)
    const float* __restrict__ prop_dist,  // (B,NS,3)
    float* __restrict__ out,              // (B,NS,768)
    int* __restrict__ cnt)                // 8 per-slice chunk counters (zeroed)
{
    unsigned xcc;
    asm volatile("s_getreg_b32 %0, hwreg(HW_REG_XCC_ID)" : "=s"(xcc));
    const int my = (int)(xcc & 7);

    __shared__ int s_chunk;
    const int t  = threadIdx.x;
    const int lp = t >> 3;                // local point 0..31
    const int cg = t & 7;                 // channel group (uint4)

    // Phase 1: own slice (L2-local). Phase 2+: steal leftovers.
    #pragma unroll 1
    for (int pass = 0; pass < NSLICE; ++pass) {
        const int slice = (my + pass) & 7;
        #pragma unroll 1
        for (;;) {
            if (t == 0) s_chunk = atomicAdd(&cnt[slice], 1);
            __syncthreads();
            const int c = s_chunk;
            __syncthreads();
            if (c >= CHUNKS) break;
            do_point(slice, y, prop_idx, prop_dist, out, c * 32 + lp, cg);
        }
    }
}

// ---------------------------------------------------------------------------
extern "C" void kernel_launch(void* const* d_in, const int* in_sizes, int n_in,
                              void* d_out, int out_size, void* d_ws, size_t ws_size,
                              hipStream_t stream) {
    const float* src       = (const float*)d_in[0];  // source_feats (B,NS,CH)
    const float* patches   = (const float*)d_in[1];  // (B,NT,K,3)
    const float* pdist     = (const float*)d_in[2];  // (B,NT,K)
    const int*   pidx      = (const int*)d_in[3];    // (B,NT,K)
    const int*   prop_idx  = (const int*)d_in[4];    // (B,NS,PP)
    const float* prop_dist = (const float*)d_in[5];  // (B,NS,PP)
    float*       out       = (float*)d_out;          // (B,NS,768)
    unsigned short* y_ws   = (unsigned short*)d_ws;  // (16, NPT, 192) bf16 = 25 MB
    int* cnt = (int*)((char*)d_ws + (size_t)16 * NPT * SC * 2);  // 8 ints after y

    hipMemsetAsync(cnt, 0, NSLICE * sizeof(int), stream);
    sh_conv_mfma<<<BATCH * NT, 256, 0, stream>>>(src, patches, pdist, pidx, y_ws);
    prop_norm_xcc<<<2048, 256, 0, stream>>>(y_ws, prop_idx, prop_dist, out, cnt);
}

// Round 8
// 105.378 us; speedup vs baseline: 2.4885x; 2.4885x over previous
//
#include <hip/hip_runtime.h>
#include <math.h>

// Problem constants (fixed by setup_inputs)
#define BATCH   2
#define NS      8192
#define NT      2048
#define KNN     64
#define CH      64
#define SC      192           // NUM_SHELLS * CH
#define NPT     4096          // BATCH * NT
#define FST     72            // featsT row stride (bf16 elems)
#define KST     72            // kern row stride
#define NSLICE  8
#define CHUNKS  512           // 16384 points / 32 per chunk
#define CPAD    32            // counter padding: 32 ints = 128 B line

typedef __attribute__((ext_vector_type(8))) short short8;
typedef __attribute__((ext_vector_type(4))) float f32x4;

// one-instruction packed f32->bf16 (RNE), lo -> bits[15:0], hi -> bits[31:16]
__device__ inline unsigned cvtpk(float lo, float hi) {
    unsigned r;
    asm("v_cvt_pk_bf16_f32 %0, %1, %2" : "=v"(r) : "v"(lo), "v"(hi));
    return r;
}
__device__ inline float blo(unsigned v) { return __uint_as_float(v << 16); }
__device__ inline float bhi(unsigned v) { return __uint_as_float(v & 0xffff0000u); }

// ---------------------------------------------------------------------------
// Kernel 1 (MFMA): UNCHANGED from rounds 5-7 (attribution control).
// y stored bf16, layout y[ys][pt][192]: each (ys,pt,s) 64-ch chunk = one
// 128 B cache line.
// ---------------------------------------------------------------------------
__global__ __launch_bounds__(256) void sh_conv_mfma(
    const float* __restrict__ src,      // (B,NS,CH)
    const float* __restrict__ patches,  // (B,NT,K,3)
    const float* __restrict__ pdist,    // (B,NT,K)
    const int*   __restrict__ pidx,     // (B,NT,K)
    unsigned short* __restrict__ y)     // (16, NPT, 192) bf16
{
    __shared__ unsigned short featsT[CH * FST];  // [c][k] 9216 B
    __shared__ unsigned short kern[48 * KST];    // [row48][k] 6912 B

    const int pt = blockIdx.x;           // b*NT + n
    const int b  = pt >> 11;             // NT = 2048
    const int t  = threadIdx.x;
    const int w  = t >> 6;               // wave 0..3
    const int l  = t & 63;               // lane

    // ---- Phase A1: gather + transpose into featsT[c=lane][k] ----
    {
        const int* idxp = pidx + pt * KNN;
        #pragma unroll
        for (int ko = 0; ko < 2; ++ko) {
            const int kbase = w * 16 + ko * 8;
            float v[8];
            #pragma unroll
            for (int j = 0; j < 8; ++j) {
                const int id = idxp[kbase + j];          // wave-uniform -> s_load
                v[j] = src[((size_t)(b * NS + id)) * CH + l];  // coalesced 256B row
            }
            uint4 pk;
            pk.x = cvtpk(v[0], v[1]);
            pk.y = cvtpk(v[2], v[3]);
            pk.z = cvtpk(v[4], v[5]);
            pk.w = cvtpk(v[6], v[7]);
            *(uint4*)&featsT[l * FST + kbase] = pk;      // ds_write_b128
        }
    }

    // ---- Phase A2: kern[row48 = ys*3+s][k] = bf16( sh[ys]*w[s]/64 ) ----
    {
        const int k  = l;
        const float* pv = patches + ((size_t)pt * KNN + k) * 3;
        const float px = pv[0], py = pv[1], pz = pv[2];
        const float d  = pdist[pt * KNN + k];
        const float inv = 1.0f / (d + 1e-8f);
        const float x = px * inv, yy = py * inv, z = pz * inv;
        const float x2 = x * x, y2 = yy * yy, z2 = z * z;

        float sh[16];
        sh[0]  = 0.28209479177387814f;
        sh[1]  = 0.4886025119029199f * yy;
        sh[2]  = 0.4886025119029199f * z;
        sh[3]  = 0.4886025119029199f * x;
        sh[4]  = 1.0925484305920792f * x * yy;
        sh[5]  = 1.0925484305920792f * yy * z;
        sh[6]  = 0.31539156525252005f * (3.0f * z2 - 1.0f);
        sh[7]  = 1.0925484305920792f * x * z;
        sh[8]  = 0.5462742152960396f * (x2 - y2);
        sh[9]  = 0.5900435899266435f * yy * (3.0f * x2 - y2);
        sh[10] = 2.890611442640554f  * x * yy * z;
        sh[11] = 0.4570457994644658f * yy * (5.0f * z2 - 1.0f);
        sh[12] = 0.3731763325901154f * z * (5.0f * z2 - 3.0f);
        sh[13] = 0.4570457994644658f * x * (5.0f * z2 - 1.0f);
        sh[14] = 1.445305721320277f  * z * (x2 - y2);
        sh[15] = 0.5900435899266435f * x * (x2 - 3.0f * y2);

        // exp(-ln2*9*t^2) == exp2(-9*t^2): one v_exp_f32 each
        float w0 = exp2f(-9.0f * d * d);
        const float dm1 = d - 0.5f;
        float w1 = exp2f(-9.0f * dm1 * dm1);
        const float dm2 = d - 1.0f;
        float w2 = exp2f(-9.0f * dm2 * dm2);
        const float wn = ((d <= 1.0f) ? 1.0f : 0.0f) * (1.0f / 64.0f)
                         / (w0 + w1 + w2 + 1e-8f);  // fold 1/K
        w0 *= wn; w1 *= wn; w2 *= wn;

        const int ys0 = w * 4;           // this wave's ys quarter
        #pragma unroll
        for (int i = 0; i < 4; ++i) {
            const float s = sh[ys0 + i];
            const int r0 = (ys0 + i) * 3;
            const float p0 = s * w0, p1 = s * w1, p2 = s * w2;
            kern[(r0 + 0) * KST + k] = (unsigned short)cvtpk(p0, p0);
            kern[(r0 + 1) * KST + k] = (unsigned short)cvtpk(p1, p1);
            kern[(r0 + 2) * KST + k] = (unsigned short)cvtpk(p2, p2);
        }
    }
    __syncthreads();

    // ---- Phase B: MFMA. lane: mhat = l&15, k-octet g = l>>4 ----
    const int mh = l & 15;
    const int g  = l >> 4;
    f32x4 acc0 = {0.f, 0.f, 0.f, 0.f};
    f32x4 acc1 = {0.f, 0.f, 0.f, 0.f};
    f32x4 acc2 = {0.f, 0.f, 0.f, 0.f};

    #pragma unroll
    for (int k0 = 0; k0 < 64; k0 += 32) {
        const int kofs = k0 + g * 8;
        const short8 af = *(const short8*)&featsT[(w * 16 + mh) * FST + kofs];
        const short8 b0 = *(const short8*)&kern[( 0 + mh) * KST + kofs];
        const short8 b1 = *(const short8*)&kern[(16 + mh) * KST + kofs];
        const short8 b2 = *(const short8*)&kern[(32 + mh) * KST + kofs];
        acc0 = __builtin_amdgcn_mfma_f32_16x16x32_bf16(af, b0, acc0, 0, 0, 0);
        acc1 = __builtin_amdgcn_mfma_f32_16x16x32_bf16(af, b1, acc1, 0, 0, 0);
        acc2 = __builtin_amdgcn_mfma_f32_16x16x32_bf16(af, b2, acc2, 0, 0, 0);
    }

    // ---- Store: lane reg r = Y^T[c = w*16+4g+r][row48 = tn*16+mh] ----
    {
        const int cbase = w * 16 + g * 4;
        #pragma unroll
        for (int tn = 0; tn < 3; ++tn) {
            const f32x4 a = (tn == 0) ? acc0 : (tn == 1) ? acc1 : acc2;
            const int row48 = tn * 16 + mh;
            const int ys = row48 / 3, s = row48 - ys * 3;
            uint2 o;
            o.x = cvtpk(a[0], a[1]);
            o.y = cvtpk(a[2], a[3]);
            *(uint2*)(y + ((size_t)ys * NPT + pt) * SC + s * CH + cbase) = o;
        }
    }
}

// ---------------------------------------------------------------------------
// Kernel 2 (XCC-queue v2): XCC-pinned slice queues — r7 proved this gives
// near-perfect L2 locality (FETCH 255->16 MB); r7's 237us was the 8 counters
// sharing ONE cache line (20K RMWs serialized on it). v2: (a) counters padded
// to 128B lines; (b) relaxed volatile pre-check turns exhausted-queue probes
// into plain loads (monotone counter => stale >=CHUNKS read is safe).
// Work/compute identical to r7; deterministic (chunk values are pure
// functions of inputs, computed exactly once).
//   slice 0..2: (3,s)        slice 3..5: (2,s)+(0,s)
//   slice 6: (1,0)+(1,1)     slice 7: (1,2)
// ---------------------------------------------------------------------------
template<int L, int S>
__device__ inline void proc_group(const unsigned short* __restrict__ y,
                                  int t0, int t1, int t2,
                                  float w0, float w1, float w2,
                                  int cg, float* __restrict__ ob)
{
    float ns[8];
    #pragma unroll
    for (int j = 0; j < 8; ++j) ns[j] = 0.f;

    #pragma unroll
    for (int m = 0; m <= 2 * L; ++m) {
        const int ys = L * L + m;
        const size_t base = (size_t)ys * NPT * SC + S * CH + cg * 8;
        const uint4 A  = *(const uint4*)(y + base + (size_t)t0 * SC);
        const uint4 Bv = *(const uint4*)(y + base + (size_t)t1 * SC);
        const uint4 Cv = *(const uint4*)(y + base + (size_t)t2 * SC);
        const unsigned aw[4] = {A.x,  A.y,  A.z,  A.w};
        const unsigned bw[4] = {Bv.x, Bv.y, Bv.z, Bv.w};
        const unsigned cw[4] = {Cv.x, Cv.y, Cv.z, Cv.w};
        #pragma unroll
        for (int q = 0; q < 4; ++q) {
            const float vlo = w0 * blo(aw[q]) + w1 * blo(bw[q]) + w2 * blo(cw[q]);
            const float vhi = w0 * bhi(aw[q]) + w1 * bhi(bw[q]) + w2 * bhi(cw[q]);
            ns[2 * q]     += vlo * vlo;
            ns[2 * q + 1] += vhi * vhi;
        }
    }

    f32x4 o0, o1;
    o0[0] = sqrtf(fmaxf(ns[0], 1e-8f));
    o0[1] = sqrtf(fmaxf(ns[1], 1e-8f));
    o0[2] = sqrtf(fmaxf(ns[2], 1e-8f));
    o0[3] = sqrtf(fmaxf(ns[3], 1e-8f));
    o1[0] = sqrtf(fmaxf(ns[4], 1e-8f));
    o1[1] = sqrtf(fmaxf(ns[5], 1e-8f));
    o1[2] = sqrtf(fmaxf(ns[6], 1e-8f));
    o1[3] = sqrtf(fmaxf(ns[7], 1e-8f));
    float* p = ob + L * SC + S * CH + cg * 8;
    __builtin_nontemporal_store(o0, (f32x4*)p);
    __builtin_nontemporal_store(o1, (f32x4*)(p + 4));
}

__device__ inline void do_point(int slice, const unsigned short* __restrict__ y,
                                const int* __restrict__ prop_idx,
                                const float* __restrict__ prop_dist,
                                float* __restrict__ out, int pt, int cg)
{
    const int b = pt >> 13;               // NS = 8192
    const int   i0 = prop_idx[pt * 3 + 0];
    const int   i1 = prop_idx[pt * 3 + 1];
    const int   i2 = prop_idx[pt * 3 + 2];
    const float d0 = prop_dist[pt * 3 + 0];
    const float d1 = prop_dist[pt * 3 + 1];
    const float d2 = prop_dist[pt * 3 + 2];

    float w0 = 1.0f / (d0 * d0 + 1e-8f);
    float w1 = 1.0f / (d1 * d1 + 1e-8f);
    float w2 = 1.0f / (d2 * d2 + 1e-8f);
    const float wi = 1.0f / (w0 + w1 + w2);
    w0 *= wi; w1 *= wi; w2 *= wi;

    const int t0 = b * NT + i0;
    const int t1 = b * NT + i1;
    const int t2 = b * NT + i2;
    float* ob = out + (size_t)pt * (4 * SC);

    switch (slice) {
    case 0: proc_group<3, 0>(y, t0, t1, t2, w0, w1, w2, cg, ob); break;
    case 1: proc_group<3, 1>(y, t0, t1, t2, w0, w1, w2, cg, ob); break;
    case 2: proc_group<3, 2>(y, t0, t1, t2, w0, w1, w2, cg, ob); break;
    case 3: proc_group<2, 0>(y, t0, t1, t2, w0, w1, w2, cg, ob);
            proc_group<0, 0>(y, t0, t1, t2, w0, w1, w2, cg, ob); break;
    case 4: proc_group<2, 1>(y, t0, t1, t2, w0, w1, w2, cg, ob);
            proc_group<0, 1>(y, t0, t1, t2, w0, w1, w2, cg, ob); break;
    case 5: proc_group<2, 2>(y, t0, t1, t2, w0, w1, w2, cg, ob);
            proc_group<0, 2>(y, t0, t1, t2, w0, w1, w2, cg, ob); break;
    case 6: proc_group<1, 0>(y, t0, t1, t2, w0, w1, w2, cg, ob);
            proc_group<1, 1>(y, t0, t1, t2, w0, w1, w2, cg, ob); break;
    default:proc_group<1, 2>(y, t0, t1, t2, w0, w1, w2, cg, ob); break;
    }
}

__global__ __launch_bounds__(256) void prop_norm_xcc(
    const unsigned short* __restrict__ y, // (16, NPT, 192) bf16
    const int*   __restrict__ prop_idx,   // (B,NS,3)
    const float* __restrict__ prop_dist,  // (B,NS,3)
    float* __restrict__ out,              // (B,NS,768)
    int* __restrict__ cnt)                // 8 x 128B-padded chunk counters
{
    unsigned xcc;
    asm volatile("s_getreg_b32 %0, hwreg(HW_REG_XCC_ID)" : "=s"(xcc));
    const int my = (int)(xcc & 7);

    __shared__ int s_chunk;
    const int t  = threadIdx.x;
    const int lp = t >> 3;                // local point 0..31
    const int cg = t & 7;                 // channel group (uint4)

    // Phase 1: own slice (L2-local). Phase 2+: steal leftovers.
    #pragma unroll 1
    for (int pass = 0; pass < NSLICE; ++pass) {
        const int slice = (my + pass) & 7;
        int* ctr = &cnt[slice * CPAD];
        #pragma unroll 1
        for (;;) {
            if (t == 0) {
                const int cur = *(volatile int*)ctr;   // cheap probe, no RMW
                s_chunk = (cur >= CHUNKS) ? CHUNKS : atomicAdd(ctr, 1);
            }
            __syncthreads();
            const int c = s_chunk;
            __syncthreads();
            if (c >= CHUNKS) break;
            do_point(slice, y, prop_idx, prop_dist, out, c * 32 + lp, cg);
        }
    }
}

// ---------------------------------------------------------------------------
extern "C" void kernel_launch(void* const* d_in, const int* in_sizes, int n_in,
                              void* d_out, int out_size, void* d_ws, size_t ws_size,
                              hipStream_t stream) {
    const float* src       = (const float*)d_in[0];  // source_feats (B,NS,CH)
    const float* patches   = (const float*)d_in[1];  // (B,NT,K,3)
    const float* pdist     = (const float*)d_in[2];  // (B,NT,K)
    const int*   pidx      = (const int*)d_in[3];    // (B,NT,K)
    const int*   prop_idx  = (const int*)d_in[4];    // (B,NS,PP)
    const float* prop_dist = (const float*)d_in[5];  // (B,NS,PP)
    float*       out       = (float*)d_out;          // (B,NS,768)
    unsigned short* y_ws   = (unsigned short*)d_ws;  // (16, NPT, 192) bf16 = 25 MB
    int* cnt = (int*)((char*)d_ws + (size_t)16 * NPT * SC * 2);  // after y

    hipMemsetAsync(cnt, 0, NSLICE * CPAD * sizeof(int), stream);
    sh_conv_mfma<<<BATCH * NT, 256, 0, stream>>>(src, patches, pdist, pidx, y_ws);
    prop_norm_xcc<<<2048, 256, 0, stream>>>(y_ws, prop_idx, prop_dist, out, cnt);
}

// Round 9
// 59.763 us; speedup vs baseline: 4.3879x; 1.7633x over previous
//
#include <hip/hip_runtime.h>
#include <math.h>

// Problem constants (fixed by setup_inputs)
#define BATCH   2
#define NS      8192
#define NT      2048
#define KNN     64
#define CH      64
#define SC      192           // NUM_SHELLS * CH
#define NPT     4096          // BATCH * NT
#define FST     72            // featsT row stride (bf16 elems)
#define KST     72            // kern row stride
#define NSLICE  8
#define CHUNKS  512           // 16384 points / 32 per chunk
#define CPAD    32            // counter padding: 32 ints = 128 B line

typedef __attribute__((ext_vector_type(8))) short short8;
typedef __attribute__((ext_vector_type(4))) float f32x4;

// one-instruction packed f32->bf16 (RNE), lo -> bits[15:0], hi -> bits[31:16]
__device__ inline unsigned cvtpk(float lo, float hi) {
    unsigned r;
    asm("v_cvt_pk_bf16_f32 %0, %1, %2" : "=v"(r) : "v"(lo), "v"(hi));
    return r;
}
__device__ inline float blo(unsigned v) { return __uint_as_float(v << 16); }
__device__ inline float bhi(unsigned v) { return __uint_as_float(v & 0xffff0000u); }

// ---------------------------------------------------------------------------
// Kernel 1 (MFMA): UNCHANGED from rounds 5-8 (attribution control).
// ---------------------------------------------------------------------------
__global__ __launch_bounds__(256) void sh_conv_mfma(
    const float* __restrict__ src,      // (B,NS,CH)
    const float* __restrict__ patches,  // (B,NT,K,3)
    const float* __restrict__ pdist,    // (B,NT,K)
    const int*   __restrict__ pidx,     // (B,NT,K)
    unsigned short* __restrict__ y)     // (16, NPT, 192) bf16
{
    __shared__ unsigned short featsT[CH * FST];  // [c][k] 9216 B
    __shared__ unsigned short kern[48 * KST];    // [row48][k] 6912 B

    const int pt = blockIdx.x;           // b*NT + n
    const int b  = pt >> 11;             // NT = 2048
    const int t  = threadIdx.x;
    const int w  = t >> 6;               // wave 0..3
    const int l  = t & 63;               // lane

    // ---- Phase A1: gather + transpose into featsT[c=lane][k] ----
    {
        const int* idxp = pidx + pt * KNN;
        #pragma unroll
        for (int ko = 0; ko < 2; ++ko) {
            const int kbase = w * 16 + ko * 8;
            float v[8];
            #pragma unroll
            for (int j = 0; j < 8; ++j) {
                const int id = idxp[kbase + j];          // wave-uniform -> s_load
                v[j] = src[((size_t)(b * NS + id)) * CH + l];  // coalesced 256B row
            }
            uint4 pk;
            pk.x = cvtpk(v[0], v[1]);
            pk.y = cvtpk(v[2], v[3]);
            pk.z = cvtpk(v[4], v[5]);
            pk.w = cvtpk(v[6], v[7]);
            *(uint4*)&featsT[l * FST + kbase] = pk;      // ds_write_b128
        }
    }

    // ---- Phase A2: kern[row48 = ys*3+s][k] = bf16( sh[ys]*w[s]/64 ) ----
    {
        const int k  = l;
        const float* pv = patches + ((size_t)pt * KNN + k) * 3;
        const float px = pv[0], py = pv[1], pz = pv[2];
        const float d  = pdist[pt * KNN + k];
        const float inv = 1.0f / (d + 1e-8f);
        const float x = px * inv, yy = py * inv, z = pz * inv;
        const float x2 = x * x, y2 = yy * yy, z2 = z * z;

        float sh[16];
        sh[0]  = 0.28209479177387814f;
        sh[1]  = 0.4886025119029199f * yy;
        sh[2]  = 0.4886025119029199f * z;
        sh[3]  = 0.4886025119029199f * x;
        sh[4]  = 1.0925484305920792f * x * yy;
        sh[5]  = 1.0925484305920792f * yy * z;
        sh[6]  = 0.31539156525252005f * (3.0f * z2 - 1.0f);
        sh[7]  = 1.0925484305920792f * x * z;
        sh[8]  = 0.5462742152960396f * (x2 - y2);
        sh[9]  = 0.5900435899266435f * yy * (3.0f * x2 - y2);
        sh[10] = 2.890611442640554f  * x * yy * z;
        sh[11] = 0.4570457994644658f * yy * (5.0f * z2 - 1.0f);
        sh[12] = 0.3731763325901154f * z * (5.0f * z2 - 3.0f);
        sh[13] = 0.4570457994644658f * x * (5.0f * z2 - 1.0f);
        sh[14] = 1.445305721320277f  * z * (x2 - y2);
        sh[15] = 0.5900435899266435f * x * (x2 - 3.0f * y2);

        // exp(-ln2*9*t^2) == exp2(-9*t^2): one v_exp_f32 each
        float w0 = exp2f(-9.0f * d * d);
        const float dm1 = d - 0.5f;
        float w1 = exp2f(-9.0f * dm1 * dm1);
        const float dm2 = d - 1.0f;
        float w2 = exp2f(-9.0f * dm2 * dm2);
        const float wn = ((d <= 1.0f) ? 1.0f : 0.0f) * (1.0f / 64.0f)
                         / (w0 + w1 + w2 + 1e-8f);  // fold 1/K
        w0 *= wn; w1 *= wn; w2 *= wn;

        const int ys0 = w * 4;           // this wave's ys quarter
        #pragma unroll
        for (int i = 0; i < 4; ++i) {
            const float s = sh[ys0 + i];
            const int r0 = (ys0 + i) * 3;
            const float p0 = s * w0, p1 = s * w1, p2 = s * w2;
            kern[(r0 + 0) * KST + k] = (unsigned short)cvtpk(p0, p0);
            kern[(r0 + 1) * KST + k] = (unsigned short)cvtpk(p1, p1);
            kern[(r0 + 2) * KST + k] = (unsigned short)cvtpk(p2, p2);
        }
    }
    __syncthreads();

    // ---- Phase B: MFMA. lane: mhat = l&15, k-octet g = l>>4 ----
    const int mh = l & 15;
    const int g  = l >> 4;
    f32x4 acc0 = {0.f, 0.f, 0.f, 0.f};
    f32x4 acc1 = {0.f, 0.f, 0.f, 0.f};
    f32x4 acc2 = {0.f, 0.f, 0.f, 0.f};

    #pragma unroll
    for (int k0 = 0; k0 < 64; k0 += 32) {
        const int kofs = k0 + g * 8;
        const short8 af = *(const short8*)&featsT[(w * 16 + mh) * FST + kofs];
        const short8 b0 = *(const short8*)&kern[( 0 + mh) * KST + kofs];
        const short8 b1 = *(const short8*)&kern[(16 + mh) * KST + kofs];
        const short8 b2 = *(const short8*)&kern[(32 + mh) * KST + kofs];
        acc0 = __builtin_amdgcn_mfma_f32_16x16x32_bf16(af, b0, acc0, 0, 0, 0);
        acc1 = __builtin_amdgcn_mfma_f32_16x16x32_bf16(af, b1, acc1, 0, 0, 0);
        acc2 = __builtin_amdgcn_mfma_f32_16x16x32_bf16(af, b2, acc2, 0, 0, 0);
    }

    // ---- Store: lane reg r = Y^T[c = w*16+4g+r][row48 = tn*16+mh] ----
    {
        const int cbase = w * 16 + g * 4;
        #pragma unroll
        for (int tn = 0; tn < 3; ++tn) {
            const f32x4 a = (tn == 0) ? acc0 : (tn == 1) ? acc1 : acc2;
            const int row48 = tn * 16 + mh;
            const int ys = row48 / 3, s = row48 - ys * 3;
            uint2 o;
            o.x = cvtpk(a[0], a[1]);
            o.y = cvtpk(a[2], a[3]);
            *(uint2*)(y + ((size_t)ys * NPT + pt) * SC + s * CH + cbase) = o;
        }
    }
}

// ---------------------------------------------------------------------------
// Kernel 2 (XCC-queue v3): locality mechanism proven (r7/r8: FETCH 255->16MB);
// v3 removes queue serialization: ONE batched grab per block (atomicAdd of 2
// chunks = 64 points), refill issued BEFORE the work so its latency hides
// under do_point, steal passes probe-first (drained lines are read-only).
// ~2-4K total RMWs spread over the kernel vs r8's ~20K hot-line ops.
// Deterministic: each chunk is a pure function computed exactly once.
//   slice 0..2: (3,s)        slice 3..5: (2,s)+(0,s)
//   slice 6: (1,0)+(1,1)     slice 7: (1,2)
// ---------------------------------------------------------------------------
template<int L, int S>
__device__ inline void proc_group(const unsigned short* __restrict__ y,
                                  int t0, int t1, int t2,
                                  float w0, float w1, float w2,
                                  int cg, float* __restrict__ ob)
{
    float ns[8];
    #pragma unroll
    for (int j = 0; j < 8; ++j) ns[j] = 0.f;

    #pragma unroll
    for (int m = 0; m <= 2 * L; ++m) {
        const int ys = L * L + m;
        const size_t base = (size_t)ys * NPT * SC + S * CH + cg * 8;
        const uint4 A  = *(const uint4*)(y + base + (size_t)t0 * SC);
        const uint4 Bv = *(const uint4*)(y + base + (size_t)t1 * SC);
        const uint4 Cv = *(const uint4*)(y + base + (size_t)t2 * SC);
        const unsigned aw[4] = {A.x,  A.y,  A.z,  A.w};
        const unsigned bw[4] = {Bv.x, Bv.y, Bv.z, Bv.w};
        const unsigned cw[4] = {Cv.x, Cv.y, Cv.z, Cv.w};
        #pragma unroll
        for (int q = 0; q < 4; ++q) {
            const float vlo = w0 * blo(aw[q]) + w1 * blo(bw[q]) + w2 * blo(cw[q]);
            const float vhi = w0 * bhi(aw[q]) + w1 * bhi(bw[q]) + w2 * bhi(cw[q]);
            ns[2 * q]     += vlo * vlo;
            ns[2 * q + 1] += vhi * vhi;
        }
    }

    f32x4 o0, o1;
    o0[0] = sqrtf(fmaxf(ns[0], 1e-8f));
    o0[1] = sqrtf(fmaxf(ns[1], 1e-8f));
    o0[2] = sqrtf(fmaxf(ns[2], 1e-8f));
    o0[3] = sqrtf(fmaxf(ns[3], 1e-8f));
    o1[0] = sqrtf(fmaxf(ns[4], 1e-8f));
    o1[1] = sqrtf(fmaxf(ns[5], 1e-8f));
    o1[2] = sqrtf(fmaxf(ns[6], 1e-8f));
    o1[3] = sqrtf(fmaxf(ns[7], 1e-8f));
    float* p = ob + L * SC + S * CH + cg * 8;
    __builtin_nontemporal_store(o0, (f32x4*)p);
    __builtin_nontemporal_store(o1, (f32x4*)(p + 4));
}

__device__ inline void do_point(int slice, const unsigned short* __restrict__ y,
                                const int* __restrict__ prop_idx,
                                const float* __restrict__ prop_dist,
                                float* __restrict__ out, int pt, int cg)
{
    const int b = pt >> 13;               // NS = 8192
    const int   i0 = prop_idx[pt * 3 + 0];
    const int   i1 = prop_idx[pt * 3 + 1];
    const int   i2 = prop_idx[pt * 3 + 2];
    const float d0 = prop_dist[pt * 3 + 0];
    const float d1 = prop_dist[pt * 3 + 1];
    const float d2 = prop_dist[pt * 3 + 2];

    float w0 = 1.0f / (d0 * d0 + 1e-8f);
    float w1 = 1.0f / (d1 * d1 + 1e-8f);
    float w2 = 1.0f / (d2 * d2 + 1e-8f);
    const float wi = 1.0f / (w0 + w1 + w2);
    w0 *= wi; w1 *= wi; w2 *= wi;

    const int t0 = b * NT + i0;
    const int t1 = b * NT + i1;
    const int t2 = b * NT + i2;
    float* ob = out + (size_t)pt * (4 * SC);

    switch (slice) {
    case 0: proc_group<3, 0>(y, t0, t1, t2, w0, w1, w2, cg, ob); break;
    case 1: proc_group<3, 1>(y, t0, t1, t2, w0, w1, w2, cg, ob); break;
    case 2: proc_group<3, 2>(y, t0, t1, t2, w0, w1, w2, cg, ob); break;
    case 3: proc_group<2, 0>(y, t0, t1, t2, w0, w1, w2, cg, ob);
            proc_group<0, 0>(y, t0, t1, t2, w0, w1, w2, cg, ob); break;
    case 4: proc_group<2, 1>(y, t0, t1, t2, w0, w1, w2, cg, ob);
            proc_group<0, 1>(y, t0, t1, t2, w0, w1, w2, cg, ob); break;
    case 5: proc_group<2, 2>(y, t0, t1, t2, w0, w1, w2, cg, ob);
            proc_group<0, 2>(y, t0, t1, t2, w0, w1, w2, cg, ob); break;
    case 6: proc_group<1, 0>(y, t0, t1, t2, w0, w1, w2, cg, ob);
            proc_group<1, 1>(y, t0, t1, t2, w0, w1, w2, cg, ob); break;
    default:proc_group<1, 2>(y, t0, t1, t2, w0, w1, w2, cg, ob); break;
    }
}

__global__ __launch_bounds__(256) void prop_norm_xcc(
    const unsigned short* __restrict__ y, // (16, NPT, 192) bf16
    const int*   __restrict__ prop_idx,   // (B,NS,3)
    const float* __restrict__ prop_dist,  // (B,NS,3)
    float* __restrict__ out,              // (B,NS,768)
    int* __restrict__ cnt)                // 8 x 128B-padded chunk counters
{
    unsigned xcc;
    asm volatile("s_getreg_b32 %0, hwreg(HW_REG_XCC_ID)" : "=s"(xcc));
    const int my = (int)(xcc & 7);

    __shared__ int s_cur;
    __shared__ int s_next;
    const int t  = threadIdx.x;
    const int lp = t >> 3;                // local point 0..31
    const int cg = t & 7;                 // channel group (uint4)

    // Phase 1: own slice (L2-local). Phase 2+: steal leftovers.
    #pragma unroll 1
    for (int pass = 0; pass < NSLICE; ++pass) {
        const int slice = (my + pass) & 7;
        int* ctr = &cnt[slice * CPAD];
        __syncthreads();                  // prior reads of s_cur/s_next done
        if (t == 0) {
            const int cur = *(volatile int*)ctr;          // cheap probe
            s_cur = (cur >= CHUNKS) ? CHUNKS : atomicAdd(ctr, 2);
        }
        __syncthreads();
        int c = s_cur;
        #pragma unroll 1
        while (c < CHUNKS) {
            __syncthreads();              // everyone has consumed s_next
            if (t == 0) s_next = atomicAdd(ctr, 2);       // refill in flight
            do_point(slice, y, prop_idx, prop_dist, out, c * 32 + lp, cg);
            if (c + 1 < CHUNKS)
                do_point(slice, y, prop_idx, prop_dist, out, (c + 1) * 32 + lp, cg);
            __syncthreads();
            c = s_next;
        }
    }
}

// ---------------------------------------------------------------------------
extern "C" void kernel_launch(void* const* d_in, const int* in_sizes, int n_in,
                              void* d_out, int out_size, void* d_ws, size_t ws_size,
                              hipStream_t stream) {
    const float* src       = (const float*)d_in[0];  // source_feats (B,NS,CH)
    const float* patches   = (const float*)d_in[1];  // (B,NT,K,3)
    const float* pdist     = (const float*)d_in[2];  // (B,NT,K)
    const int*   pidx      = (const int*)d_in[3];    // (B,NT,K)
    const int*   prop_idx  = (const int*)d_in[4];    // (B,NS,PP)
    const float* prop_dist = (const float*)d_in[5];  // (B,NS,PP)
    float*       out       = (float*)d_out;          // (B,NS,768)
    unsigned short* y_ws   = (unsigned short*)d_ws;  // (16, NPT, 192) bf16 = 25 MB
    int* cnt = (int*)((char*)d_ws + (size_t)16 * NPT * SC * 2);  // after y

    hipMemsetAsync(cnt, 0, NSLICE * CPAD * sizeof(int), stream);
    sh_conv_mfma<<<BATCH * NT, 256, 0, stream>>>(src, patches, pdist, pidx, y_ws);
    prop_norm_xcc<<<2048, 256, 0, stream>>>(y_ws, prop_idx, prop_dist, out, cnt);
}

// Round 10
// 49.780 us; speedup vs baseline: 5.2679x; 1.2006x over previous
//
#include <hip/hip_runtime.h>
#include <math.h>

// Problem constants (fixed by setup_inputs)
#define BATCH   2
#define NS      8192
#define NT      2048
#define KNN     64
#define CH      64
#define SC      192           // NUM_SHELLS * CH
#define NPT     4096          // BATCH * NT
#define FST     72            // featsT row stride (bf16 elems)
#define KST     72            // kern row stride
#define SST     72            // staged-y shell stride (bf16 elems, 144B)
#define YST     224           // staged-y ys stride (3*72+8, 448B, 16B-aligned)

typedef __attribute__((ext_vector_type(8))) short short8;
typedef __attribute__((ext_vector_type(4))) float f32x4;

// one-instruction packed f32->bf16 (RNE), lo -> bits[15:0], hi -> bits[31:16]
__device__ inline unsigned cvtpk(float lo, float hi) {
    unsigned r;
    asm("v_cvt_pk_bf16_f32 %0, %1, %2" : "=v"(r) : "v"(lo), "v"(hi));
    return r;
}
__device__ inline float blo(unsigned v) { return __uint_as_float(v << 16); }
__device__ inline float bhi(unsigned v) { return __uint_as_float(v & 0xffff0000u); }

// ---------------------------------------------------------------------------
// Kernel 1 (MFMA, LDS-staged store): gather/A2/MFMA identical to rounds 5-9.
// NEW: epilogue stages the 6KB per-point result in LDS, then writes y with
// full-128B-line coalesced stores (was: ~786K scattered 32B segments; now:
// ~196K full lines). y layout unchanged: y[ys][pt][192] bf16.
// ---------------------------------------------------------------------------
__global__ __launch_bounds__(256) void sh_conv_mfma(
    const float* __restrict__ src,      // (B,NS,CH)
    const float* __restrict__ patches,  // (B,NT,K,3)
    const float* __restrict__ pdist,    // (B,NT,K)
    const int*   __restrict__ pidx,     // (B,NT,K)
    unsigned short* __restrict__ y)     // (16, NPT, 192) bf16
{
    __shared__ unsigned short featsT[CH * FST];  // [c][k] 9216 B (reused for stage)
    __shared__ unsigned short kern[48 * KST];    // [row48][k] 6912 B

    const int pt = blockIdx.x;           // b*NT + n
    const int b  = pt >> 11;             // NT = 2048
    const int t  = threadIdx.x;
    const int w  = t >> 6;               // wave 0..3
    const int l  = t & 63;               // lane

    // ---- Phase A1: gather + transpose into featsT[c=lane][k] ----
    {
        const int* idxp = pidx + pt * KNN;
        #pragma unroll
        for (int ko = 0; ko < 2; ++ko) {
            const int kbase = w * 16 + ko * 8;
            float v[8];
            #pragma unroll
            for (int j = 0; j < 8; ++j) {
                const int id = idxp[kbase + j];          // wave-uniform -> s_load
                v[j] = src[((size_t)(b * NS + id)) * CH + l];  // coalesced 256B row
            }
            uint4 pk;
            pk.x = cvtpk(v[0], v[1]);
            pk.y = cvtpk(v[2], v[3]);
            pk.z = cvtpk(v[4], v[5]);
            pk.w = cvtpk(v[6], v[7]);
            *(uint4*)&featsT[l * FST + kbase] = pk;      // ds_write_b128
        }
    }

    // ---- Phase A2: kern[row48 = ys*3+s][k] = bf16( sh[ys]*w[s]/64 ) ----
    {
        const int k  = l;
        const float* pv = patches + ((size_t)pt * KNN + k) * 3;
        const float px = pv[0], py = pv[1], pz = pv[2];
        const float d  = pdist[pt * KNN + k];
        const float inv = 1.0f / (d + 1e-8f);
        const float x = px * inv, yy = py * inv, z = pz * inv;
        const float x2 = x * x, y2 = yy * yy, z2 = z * z;

        float sh[16];
        sh[0]  = 0.28209479177387814f;
        sh[1]  = 0.4886025119029199f * yy;
        sh[2]  = 0.4886025119029199f * z;
        sh[3]  = 0.4886025119029199f * x;
        sh[4]  = 1.0925484305920792f * x * yy;
        sh[5]  = 1.0925484305920792f * yy * z;
        sh[6]  = 0.31539156525252005f * (3.0f * z2 - 1.0f);
        sh[7]  = 1.0925484305920792f * x * z;
        sh[8]  = 0.5462742152960396f * (x2 - y2);
        sh[9]  = 0.5900435899266435f * yy * (3.0f * x2 - y2);
        sh[10] = 2.890611442640554f  * x * yy * z;
        sh[11] = 0.4570457994644658f * yy * (5.0f * z2 - 1.0f);
        sh[12] = 0.3731763325901154f * z * (5.0f * z2 - 3.0f);
        sh[13] = 0.4570457994644658f * x * (5.0f * z2 - 1.0f);
        sh[14] = 1.445305721320277f  * z * (x2 - y2);
        sh[15] = 0.5900435899266435f * x * (x2 - 3.0f * y2);

        // exp(-ln2*9*t^2) == exp2(-9*t^2): one v_exp_f32 each
        float w0 = exp2f(-9.0f * d * d);
        const float dm1 = d - 0.5f;
        float w1 = exp2f(-9.0f * dm1 * dm1);
        const float dm2 = d - 1.0f;
        float w2 = exp2f(-9.0f * dm2 * dm2);
        const float wn = ((d <= 1.0f) ? 1.0f : 0.0f) * (1.0f / 64.0f)
                         / (w0 + w1 + w2 + 1e-8f);  // fold 1/K
        w0 *= wn; w1 *= wn; w2 *= wn;

        const int ys0 = w * 4;           // this wave's ys quarter
        #pragma unroll
        for (int i = 0; i < 4; ++i) {
            const float s = sh[ys0 + i];
            const int r0 = (ys0 + i) * 3;
            const float p0 = s * w0, p1 = s * w1, p2 = s * w2;
            kern[(r0 + 0) * KST + k] = (unsigned short)cvtpk(p0, p0);
            kern[(r0 + 1) * KST + k] = (unsigned short)cvtpk(p1, p1);
            kern[(r0 + 2) * KST + k] = (unsigned short)cvtpk(p2, p2);
        }
    }
    __syncthreads();

    // ---- Phase B: MFMA. lane: mhat = l&15, k-octet g = l>>4 ----
    const int mh = l & 15;
    const int g  = l >> 4;
    f32x4 acc0 = {0.f, 0.f, 0.f, 0.f};
    f32x4 acc1 = {0.f, 0.f, 0.f, 0.f};
    f32x4 acc2 = {0.f, 0.f, 0.f, 0.f};

    #pragma unroll
    for (int k0 = 0; k0 < 64; k0 += 32) {
        const int kofs = k0 + g * 8;
        const short8 af = *(const short8*)&featsT[(w * 16 + mh) * FST + kofs];
        const short8 b0 = *(const short8*)&kern[( 0 + mh) * KST + kofs];
        const short8 b1 = *(const short8*)&kern[(16 + mh) * KST + kofs];
        const short8 b2 = *(const short8*)&kern[(32 + mh) * KST + kofs];
        acc0 = __builtin_amdgcn_mfma_f32_16x16x32_bf16(af, b0, acc0, 0, 0, 0);
        acc1 = __builtin_amdgcn_mfma_f32_16x16x32_bf16(af, b1, acc1, 0, 0, 0);
        acc2 = __builtin_amdgcn_mfma_f32_16x16x32_bf16(af, b2, acc2, 0, 0, 0);
    }

    // ---- Stage: lane reg r = Y^T[c = w*16+4g+r][row48 = tn*16+mh]
    //      -> lds_y[ys*YST + s*SST + c] (bf16), then coalesced line writes.
    __syncthreads();                     // all LDS reads of featsT/kern done
    unsigned short* lds_y = featsT;      // 16*YST = 3584 elems = 7168 B, fits
    {
        const int c0 = w * 16 + g * 4;
        #pragma unroll
        for (int tn = 0; tn < 3; ++tn) {
            const f32x4 a = (tn == 0) ? acc0 : (tn == 1) ? acc1 : acc2;
            const int row48 = tn * 16 + mh;
            const int ys = row48 / 3, s = row48 - ys * 3;
            uint2 o;
            o.x = cvtpk(a[0], a[1]);
            o.y = cvtpk(a[2], a[3]);
            *(uint2*)&lds_y[ys * YST + s * SST + c0] = o;
        }
    }
    __syncthreads();

    // ---- Write: 384 x 16B segments; each 8 consecutive lanes = one full
    //      128B line of y[ys][pt][.]. 2 passes over 256 threads.
    {
        #pragma unroll
        for (int p = 0; p < 2; ++p) {
            const int idx = p * 256 + t;
            if (idx < 384) {
                const int ys  = idx / 24;
                const int c24 = idx - ys * 24;       // 0..23, 16B units
                const int s   = c24 >> 3;
                const int ch  = (c24 & 7) * 8;
                const uint4 v = *(const uint4*)&lds_y[ys * YST + s * SST + ch];
                *(uint4*)(y + ((size_t)ys * NPT + pt) * SC + c24 * 8) = v;
            }
        }
    }
}

// ---------------------------------------------------------------------------
// Kernel 2: reverted to round-6 plain sliced form (best measured: K2 ~35us,
// the L2->CU line-delivery wall; queue variants only added overhead).
// Norms are column-separable; slot (blockIdx&7) owns a disjoint (l,s) subset.
//   slot 0..2: (3,s)  [7 ys]     slot 3..5: (2,s)  [5 ys]
//   slot 6: (1,0)+(1,1) [6]      slot 7: (1,2)+(0,0)+(0,1)+(0,2) [6]
// Block: 256 thr = 32 points x 8 ch-groups (uint4 = 8 channels each).
// ---------------------------------------------------------------------------
template<int L, int S>
__device__ inline void proc_group(const unsigned short* __restrict__ y,
                                  int t0, int t1, int t2,
                                  float w0, float w1, float w2,
                                  int cg, float* __restrict__ ob)
{
    float ns[8];
    #pragma unroll
    for (int j = 0; j < 8; ++j) ns[j] = 0.f;

    #pragma unroll
    for (int m = 0; m <= 2 * L; ++m) {
        const int ys = L * L + m;
        const size_t base = (size_t)ys * NPT * SC + S * CH + cg * 8;
        const uint4 A  = *(const uint4*)(y + base + (size_t)t0 * SC);
        const uint4 Bv = *(const uint4*)(y + base + (size_t)t1 * SC);
        const uint4 Cv = *(const uint4*)(y + base + (size_t)t2 * SC);
        const unsigned aw[4] = {A.x,  A.y,  A.z,  A.w};
        const unsigned bw[4] = {Bv.x, Bv.y, Bv.z, Bv.w};
        const unsigned cw[4] = {Cv.x, Cv.y, Cv.z, Cv.w};
        #pragma unroll
        for (int q = 0; q < 4; ++q) {
            const float vlo = w0 * blo(aw[q]) + w1 * blo(bw[q]) + w2 * blo(cw[q]);
            const float vhi = w0 * bhi(aw[q]) + w1 * bhi(bw[q]) + w2 * bhi(cw[q]);
            ns[2 * q]     += vlo * vlo;
            ns[2 * q + 1] += vhi * vhi;
        }
    }

    f32x4 o0, o1;
    o0[0] = sqrtf(fmaxf(ns[0], 1e-8f));
    o0[1] = sqrtf(fmaxf(ns[1], 1e-8f));
    o0[2] = sqrtf(fmaxf(ns[2], 1e-8f));
    o0[3] = sqrtf(fmaxf(ns[3], 1e-8f));
    o1[0] = sqrtf(fmaxf(ns[4], 1e-8f));
    o1[1] = sqrtf(fmaxf(ns[5], 1e-8f));
    o1[2] = sqrtf(fmaxf(ns[6], 1e-8f));
    o1[3] = sqrtf(fmaxf(ns[7], 1e-8f));
    float* p = ob + L * SC + S * CH + cg * 8;
    __builtin_nontemporal_store(o0, (f32x4*)p);
    __builtin_nontemporal_store(o1, (f32x4*)(p + 4));
}

__global__ __launch_bounds__(256) void prop_norm_sliced(
    const unsigned short* __restrict__ y, // (16, NPT, 192) bf16
    const int*   __restrict__ prop_idx,   // (B,NS,3)
    const float* __restrict__ prop_dist,  // (B,NS,3)
    float* __restrict__ out)              // (B,NS,768)
{
    const int slot = blockIdx.x & 7;
    const int bi   = blockIdx.x >> 3;
    const int t    = threadIdx.x;
    const int lp   = t >> 3;              // local point 0..31
    const int cg   = t & 7;               // channel group (8 ch, uint4)
    const int pt   = bi * 32 + lp;        // b*NS + ns
    const int b    = pt >> 13;            // NS = 8192

    const int   i0 = prop_idx[pt * 3 + 0];
    const int   i1 = prop_idx[pt * 3 + 1];
    const int   i2 = prop_idx[pt * 3 + 2];
    const float d0 = prop_dist[pt * 3 + 0];
    const float d1 = prop_dist[pt * 3 + 1];
    const float d2 = prop_dist[pt * 3 + 2];

    float w0 = 1.0f / (d0 * d0 + 1e-8f);
    float w1 = 1.0f / (d1 * d1 + 1e-8f);
    float w2 = 1.0f / (d2 * d2 + 1e-8f);
    const float wi = 1.0f / (w0 + w1 + w2);
    w0 *= wi; w1 *= wi; w2 *= wi;

    const int t0 = b * NT + i0;
    const int t1 = b * NT + i1;
    const int t2 = b * NT + i2;
    float* ob = out + (size_t)pt * (4 * SC);

    switch (slot) {
    case 0: proc_group<3, 0>(y, t0, t1, t2, w0, w1, w2, cg, ob); break;
    case 1: proc_group<3, 1>(y, t0, t1, t2, w0, w1, w2, cg, ob); break;
    case 2: proc_group<3, 2>(y, t0, t1, t2, w0, w1, w2, cg, ob); break;
    case 3: proc_group<2, 0>(y, t0, t1, t2, w0, w1, w2, cg, ob); break;
    case 4: proc_group<2, 1>(y, t0, t1, t2, w0, w1, w2, cg, ob); break;
    case 5: proc_group<2, 2>(y, t0, t1, t2, w0, w1, w2, cg, ob); break;
    case 6: proc_group<1, 0>(y, t0, t1, t2, w0, w1, w2, cg, ob);
            proc_group<1, 1>(y, t0, t1, t2, w0, w1, w2, cg, ob); break;
    default:proc_group<1, 2>(y, t0, t1, t2, w0, w1, w2, cg, ob);
            proc_group<0, 0>(y, t0, t1, t2, w0, w1, w2, cg, ob);
            proc_group<0, 1>(y, t0, t1, t2, w0, w1, w2, cg, ob);
            proc_group<0, 2>(y, t0, t1, t2, w0, w1, w2, cg, ob); break;
    }
}

// ---------------------------------------------------------------------------
extern "C" void kernel_launch(void* const* d_in, const int* in_sizes, int n_in,
                              void* d_out, int out_size, void* d_ws, size_t ws_size,
                              hipStream_t stream) {
    const float* src       = (const float*)d_in[0];  // source_feats (B,NS,CH)
    const float* patches   = (const float*)d_in[1];  // (B,NT,K,3)
    const float* pdist     = (const float*)d_in[2];  // (B,NT,K)
    const int*   pidx      = (const int*)d_in[3];    // (B,NT,K)
    const int*   prop_idx  = (const int*)d_in[4];    // (B,NS,PP)
    const float* prop_dist = (const float*)d_in[5];  // (B,NS,PP)
    float*       out       = (float*)d_out;          // (B,NS,768)
    unsigned short* y_ws   = (unsigned short*)d_ws;  // (16, NPT, 192) bf16 = 25 MB

    sh_conv_mfma<<<BATCH * NT, 256, 0, stream>>>(src, patches, pdist, pidx, y_ws);
    prop_norm_sliced<<<8 * (BATCH * NS / 32), 256, 0, stream>>>(y_ws, prop_idx, prop_dist, out);
}